// Round 1
// baseline (121.612 us; speedup 1.0000x reference)
//
#include <hip/hip_runtime.h>

// PiecewisePolynomial: out[b,o] = sum_i sum_j L_j(x_in(b,i)) * w[o, i, 3*seg(b,i)+j]
// B=512, IN_F=256, OUT_F=256, SEGMENTS=16, N=4 (nodes -1,-0.5,0.5,1)

#define BATCH   512
#define INF     256
#define OUTF    256
#define NSEG    16
#define WSTRIDE 49                 // (N-1)*SEGMENTS+1
#define OSTRIDE (INF * WSTRIDE)    // 12544

#define OT 64     // o-tile (one wave width)
#define IC 4      // i's per block
#define BT 256    // b's per block (4 waves x 64)

// LDS tile: [IC][OT][64 slots of (s,j)] fp32, slot swizzled by o to kill bank conflicts.
// 4*64*64*4 = 65536 B exactly.

__global__ __launch_bounds__(256, 2)
void pp_kernel(const float* __restrict__ x, const float* __restrict__ w,
               float* __restrict__ out) {
    __shared__ float w_e[IC * OT * 64];

    const int tid    = threadIdx.x;
    const int i_base = blockIdx.x * IC;
    const int o_base = blockIdx.y * OT;
    const int b_base = blockIdx.z * BT;

    // ---- stage + expand w[o_tile, i_chunk, 0..48] -> w_e[i][o][slot(s,o)*4+j] ----
    {
        const float* wp = w + o_base * OSTRIDE + i_base * WSTRIDE;
        for (int q = 0; q < 49; ++q) {
            int f   = q * 256 + tid;         // 0..12543 (=64*4*49)
            int o   = f / 196;               // 196 = IC*WSTRIDE
            int rem = f - o * 196;
            int i   = rem / 49;
            int t   = rem - i * 49;
            float v = wp[o * OSTRIDE + i * WSTRIDE + t];
            int j0  = t % 3;                 // t = 3*s0 + j0
            int s0  = (t - j0) / 3;
            int row = (i * OT + o) * 64;
            // slot swizzle: consecutive o -> rotated s-groups (conflict-free b128)
            if (s0 < NSEG)
                w_e[row + (((s0 + o) & 15) << 2) + j0] = v;
            if (j0 == 0 && s0 > 0)           // t=3*s0 is also (s0-1, j=3)
                w_e[row + ((((s0 - 1) + o) & 15) << 2) + 3] = v;
        }
    }
    __syncthreads();

    const int wave = tid >> 6;
    const int lane = tid & 63;
    const int b0   = b_base + wave * 64;     // this wave's 64 batch rows
    const int o    = o_base + lane;          // this lane's output column

    // ---- per-lane basis for its OWN b at the 4 staged i's ----
    float4 xv = *(const float4*)(x + (b0 + lane) * INF + i_base);
    float Ls[IC][4];
    int   sid[IC];
    #pragma unroll
    for (int i = 0; i < IC; ++i) {
        float xx = (&xv.x)[i];
        int id = (int)((xx + 1.0f) * 8.0f);        // == (x+1)/2*16, trunc
        id = id < 0 ? 0 : (id > 15 ? 15 : id);
        float x_min = (float)id * 0.125f - 1.0f;   // id/16*2-1
        float u = (xx - x_min) * 16.0f - 1.0f;     // 2*(x-x_min)/0.125 - 1
        float a = u + 1.0f, bb = u + 0.5f, c = u - 0.5f, d = u - 1.0f;
        Ls[i][0] = bb * c * d * (-2.0f / 3.0f);
        Ls[i][1] = a  * c * d * ( 4.0f / 3.0f);
        Ls[i][2] = a  * bb * d * (-4.0f / 3.0f);
        Ls[i][3] = a  * bb * c * ( 2.0f / 3.0f);
        sid[i] = id;
    }

    // per-i LDS row base for this lane's o
    int rowb[IC];
    #pragma unroll
    for (int i = 0; i < IC; ++i) rowb[i] = (i * OT + lane) * 64;

    // ---- main loop: broadcast (seg, basis) of batch b0+k via readlane,
    //      one conflict-free ds_read_b128 + 4 fmac per (b, i) ----
    #pragma unroll 4
    for (int k = 0; k < 64; ++k) {
        float acc = 0.0f;
        #pragma unroll
        for (int i = 0; i < IC; ++i) {
            int   s  = __builtin_amdgcn_readlane(sid[i], k);
            float c0 = __int_as_float(__builtin_amdgcn_readlane(__float_as_int(Ls[i][0]), k));
            float c1 = __int_as_float(__builtin_amdgcn_readlane(__float_as_int(Ls[i][1]), k));
            float c2 = __int_as_float(__builtin_amdgcn_readlane(__float_as_int(Ls[i][2]), k));
            float c3 = __int_as_float(__builtin_amdgcn_readlane(__float_as_int(Ls[i][3]), k));
            const float4 wv = *(const float4*)&w_e[rowb[i] + (((s + lane) & 15) << 2)];
            acc += c0 * wv.x + c1 * wv.y + c2 * wv.z + c3 * wv.w;
        }
        atomicAdd(&out[(b0 + k) * OUTF + o], acc);
    }
}

extern "C" void kernel_launch(void* const* d_in, const int* in_sizes, int n_in,
                              void* d_out, int out_size, void* d_ws, size_t ws_size,
                              hipStream_t stream) {
    const float* x = (const float*)d_in[0];
    const float* w = (const float*)d_in[1];
    float* out = (float*)d_out;
    (void)d_ws; (void)ws_size; (void)n_in; (void)in_sizes;

    hipMemsetAsync(out, 0, (size_t)out_size * sizeof(float), stream);

    dim3 grid(INF / IC, OUTF / OT, BATCH / BT);  // (64, 4, 2) = 512 blocks
    pp_kernel<<<grid, 256, 0, stream>>>(x, w, out);
}

// Round 2
// 97.277 us; speedup vs baseline: 1.2502x; 1.2502x over previous
//
#include <hip/hip_runtime.h>

// PiecewisePolynomial: out[b,o] = sum_i sum_j L_j(x_in(b,i)) * w[o, i, 3*seg(b,i)+j]
// B=512, IN_F=256, OUT_F=256, SEGMENTS=16, N=4 (nodes -1,-0.5,0.5,1)
//
// R2 design: lane = batch row (own basis/seg in regs, zero broadcast),
// acc[o] register-resident across 8 i's (atomics halved to 16.8MB),
// async global_load_lds double-buffered staging, LDS-transpose for
// coalesced atomic epilogue.

#define INF     256
#define OUTF    256
#define WSTRIDE 49                  // (N-1)*SEGMENTS+1
#define OSTRIDE (INF * WSTRIDE)     // 12544

#define GLOAD_LDS(gptr, lptr)                                                       \
  __builtin_amdgcn_global_load_lds(                                                 \
      (const __attribute__((address_space(1))) unsigned int*)(gptr),                \
      (__attribute__((address_space(3))) unsigned int*)(lptr), 4, 0, 0)

__global__ __launch_bounds__(256, 1)
void pp_kernel(const float* __restrict__ x, const float* __restrict__ w,
               float* __restrict__ out) {
    // Two 64KiB tile buffers: smem[buf*16384 + (i*64+o)*64 + s*4 + j]
    // (i: chunk-local 0..3, o: 0..63, s: 0..15, j: 0..3). Reused for transpose.
    __shared__ float smem[32768];

    const int tid  = threadIdx.x;
    const int wave = tid >> 6;
    const int lane = tid & 63;
    const int i_base = blockIdx.x * 8;    // 32 i-splits of 8
    const int o_base = blockIdx.y * 64;   // 4 o-tiles
    const int b_base = blockIdx.z * 256;  // 2 b-tiles
    const int b_me   = b_base + tid;      // this thread's batch row

    // ---- per-lane basis + segment for own b at the 8 staged i's (registers) ----
    float c[8][4];
    int   sseg[8];
    {
        const float4* xp = (const float4*)(x + (size_t)b_me * INF + i_base);
        float4 xv0 = xp[0], xv1 = xp[1];
        float xs[8] = {xv0.x, xv0.y, xv0.z, xv0.w, xv1.x, xv1.y, xv1.z, xv1.w};
        #pragma unroll
        for (int i = 0; i < 8; ++i) {
            float xx = xs[i];
            int id = (int)((xx + 1.0f) * 8.0f);
            id = id < 0 ? 0 : (id > 15 ? 15 : id);
            float u = (xx - ((float)id * 0.125f - 1.0f)) * 16.0f - 1.0f;
            float a = u + 1.0f, b2 = u + 0.5f, cc = u - 0.5f, d = u - 1.0f;
            c[i][0] = b2 * cc * d * (-2.0f / 3.0f);
            c[i][1] = a  * cc * d * ( 4.0f / 3.0f);
            c[i][2] = a  * b2 * d * (-4.0f / 3.0f);
            c[i][3] = a  * b2 * cc * ( 2.0f / 3.0f);
            sseg[i] = id;
        }
    }

    // ---- async staging: expand w[o, i, t] -> slot layout via per-lane gather ----
    // lane L covers (slot = L>>2, j = L&3) -> t = 3*slot + j (j==3 is shared node)
    const int lane_t = 3 * (lane >> 2) + (lane & 3);

    #define STAGE(ci)                                                                 \
    do {                                                                              \
        const int bufd_ = (ci & 1) * 16384;                                           \
        for (int t = 0; t < 64; ++t) {                                                \
            int r = t * 4 + wave;            /* rows 0..255 = (i_loc*64 + o) */       \
            int i_loc = r >> 6, o = r & 63;                                           \
            const float* gp = w + (size_t)(o_base + o) * OSTRIDE                      \
                                + (i_base + (ci) * 4 + i_loc) * WSTRIDE + lane_t;     \
            GLOAD_LDS(gp, &smem[bufd_ + r * 64]);                                     \
        }                                                                             \
    } while (0)

    float acc[64];
    #pragma unroll
    for (int o = 0; o < 64; ++o) acc[o] = 0.0f;

    #define COMPUTE(ci)                                                               \
    do {                                                                              \
        const float* p0 = &smem[(ci & 1) * 16384 +     0 + sseg[(ci)*4 + 0] * 4];     \
        const float* p1 = &smem[(ci & 1) * 16384 +  4096 + sseg[(ci)*4 + 1] * 4];     \
        const float* p2 = &smem[(ci & 1) * 16384 +  8192 + sseg[(ci)*4 + 2] * 4];     \
        const float* p3 = &smem[(ci & 1) * 16384 + 12288 + sseg[(ci)*4 + 3] * 4];     \
        _Pragma("unroll")                                                             \
        for (int o = 0; o < 64; ++o) {                                                \
            float4 w0 = *(const float4*)(p0 + o * 64);                                \
            float4 w1 = *(const float4*)(p1 + o * 64);                                \
            float4 w2 = *(const float4*)(p2 + o * 64);                                \
            float4 w3 = *(const float4*)(p3 + o * 64);                                \
            float t0 = acc[o];                                                        \
            t0 += c[(ci)*4+0][0]*w0.x; t0 += c[(ci)*4+0][1]*w0.y;                     \
            t0 += c[(ci)*4+0][2]*w0.z; t0 += c[(ci)*4+0][3]*w0.w;                     \
            t0 += c[(ci)*4+1][0]*w1.x; t0 += c[(ci)*4+1][1]*w1.y;                     \
            t0 += c[(ci)*4+1][2]*w1.z; t0 += c[(ci)*4+1][3]*w1.w;                     \
            t0 += c[(ci)*4+2][0]*w2.x; t0 += c[(ci)*4+2][1]*w2.y;                     \
            t0 += c[(ci)*4+2][2]*w2.z; t0 += c[(ci)*4+2][3]*w2.w;                     \
            t0 += c[(ci)*4+3][0]*w3.x; t0 += c[(ci)*4+3][1]*w3.y;                     \
            t0 += c[(ci)*4+3][2]*w3.z; t0 += c[(ci)*4+3][3]*w3.w;                     \
            acc[o] = t0;                                                              \
        }                                                                             \
    } while (0)

    STAGE(0);
    __syncthreads();          // drain stage(0), buf0 ready
    STAGE(1);                 // async: in flight during compute(0)
    COMPUTE(0);
    __syncthreads();          // drain stage(1) + all waves done with buf0
    COMPUTE(1);
    __syncthreads();          // everyone done reading buf1 before reuse as transpose

    // ---- transpose acc (lane=b) -> coalesced rows (lane=o), then one atomic pass --
    // tr[b_local][o] with stride 65 (bank = b_local + o mod 32 -> <=2-way)
    #pragma unroll
    for (int o = 0; o < 64; ++o) smem[tid * 65 + o] = acc[o];
    __syncthreads();

    const int bg = b_base + wave * 64;
    for (int r = 0; r < 64; ++r) {
        float v = smem[(wave * 64 + r) * 65 + lane];
        atomicAdd(&out[(size_t)(bg + r) * OUTF + o_base + lane], v);
    }

    #undef STAGE
    #undef COMPUTE
}

extern "C" void kernel_launch(void* const* d_in, const int* in_sizes, int n_in,
                              void* d_out, int out_size, void* d_ws, size_t ws_size,
                              hipStream_t stream) {
    const float* x = (const float*)d_in[0];
    const float* w = (const float*)d_in[1];
    float* out = (float*)d_out;
    (void)d_ws; (void)ws_size; (void)n_in; (void)in_sizes;

    hipMemsetAsync(out, 0, (size_t)out_size * sizeof(float), stream);

    dim3 grid(32, 4, 2);   // (i-splits, o-tiles, b-tiles) = 256 blocks, 1/CU
    pp_kernel<<<grid, 256, 0, stream>>>(x, w, out);
}

// Round 3
// 87.874 us; speedup vs baseline: 1.3839x; 1.1070x over previous
//
#include <hip/hip_runtime.h>

// PiecewisePolynomial: out[b,o] = sum_i sum_j L_j(x_in(b,i)) * w[o, i, 3*seg(b,i)+j]
// B=512, IN_F=256, OUT_F=256, SEGMENTS=16, N=4 (nodes -1,-0.5,0.5,1)
//
// R3: no atomics (split-i partials to d_ws + reduce kernel), 64KB LDS ->
// 2 blocks/CU (8 waves/CU), lane=b seg-indexed ds_read_b128 inner loop.

#define INF     256
#define OUTF    256
#define WSTRIDE 49                  // (N-1)*SEGMENTS+1
#define OSTRIDE (INF * WSTRIDE)     // 12544

#define NSPLIT  32                  // i-splits (blocks along i)
#define IPB     8                   // i's per block
#define ICH     2                   // i's per staged chunk (double-buffered)

#define GLOAD_LDS(gptr, lptr)                                                       \
  __builtin_amdgcn_global_load_lds(                                                 \
      (const __attribute__((address_space(1))) unsigned int*)(gptr),                \
      (__attribute__((address_space(3))) unsigned int*)(lptr), 4, 0, 0)

// Stage chunk ci: w[o_tile 64][2 i][slots 64] -> buf (ci&1). 128 rows of 64
// dwords; per-lane gather t = 3*(lane>>2)+(lane&3) expands 49 -> 64 slot dwords.
#define STAGE(ci)                                                                   \
do {                                                                                \
    float* lbase_ = &smem[((ci) & 1) * 8192];                                       \
    _Pragma("unroll")                                                               \
    for (int t = 0; t < 32; ++t) {                                                  \
        int r_ = t * 4 + wave;             /* row = i_loc*64 + o */                 \
        int i_loc_ = r_ >> 6, o_ = r_ & 63;                                         \
        const float* gp_ = w + (size_t)(o_base + o_) * OSTRIDE                      \
                             + (i_base + (ci) * ICH + i_loc_) * WSTRIDE + lane_t;   \
        GLOAD_LDS(gp_, lbase_ + r_ * 64);                                           \
    }                                                                               \
} while (0)

// Compute chunk ci: per i, one seg-indexed ds_read_b128 per o (broadcast for
// same-seg lanes; distinct segs 16B apart -> <=2-way bank alias = free).
#define COMPUTE(ci)                                                                 \
do {                                                                                \
    _Pragma("unroll")                                                               \
    for (int il = 0; il < ICH; ++il) {                                              \
        const int ig_ = (ci) * ICH + il;                                            \
        const float* p_ = &smem[((ci) & 1) * 8192 +                                 \
                                (il * 64 + oh * 32) * 64 + sseg[ig_] * 4];          \
        const float c0_ = c[ig_][0], c1_ = c[ig_][1];                               \
        const float c2_ = c[ig_][2], c3_ = c[ig_][3];                               \
        _Pragma("unroll")                                                           \
        for (int oo = 0; oo < 32; ++oo) {                                           \
            float4 wv_ = *(const float4*)(p_ + oo * 64);                            \
            acc[oo] += c0_ * wv_.x + c1_ * wv_.y + c2_ * wv_.z + c3_ * wv_.w;       \
        }                                                                           \
    }                                                                               \
} while (0)

__global__ __launch_bounds__(256, 2)
void pp_partial(const float* __restrict__ x, const float* __restrict__ w,
                float* __restrict__ ws) {
    __shared__ float smem[16384];   // 2 bufs x (2i x 64o x 64slot) = 64 KB

    const int tid  = threadIdx.x;
    const int wave = tid >> 6, lane = tid & 63;
    const int isplit = blockIdx.x;              // 0..31
    const int i_base = isplit * IPB;
    const int o_base = blockIdx.y * 64;         // 0..3
    const int b_base = blockIdx.z * 128;        // 0..3
    const int bh = wave >> 1, oh = wave & 1;    // wave -> (b-half, o-half)
    const int b  = b_base + bh * 64 + lane;     // this lane's batch row
    const int lane_t = 3 * (lane >> 2) + (lane & 3);

    // ---- per-lane basis + segment for own b at the 8 staged i's ----
    float c[IPB][4];
    int   sseg[IPB];
    {
        const float4* xp = (const float4*)(x + (size_t)b * INF + i_base);
        float4 x0 = xp[0], x1 = xp[1];
        float xs[8] = {x0.x, x0.y, x0.z, x0.w, x1.x, x1.y, x1.z, x1.w};
        #pragma unroll
        for (int i = 0; i < IPB; ++i) {
            float xx = xs[i];
            int id = (int)((xx + 1.0f) * 8.0f);
            id = id < 0 ? 0 : (id > 15 ? 15 : id);
            float u = (xx - ((float)id * 0.125f - 1.0f)) * 16.0f - 1.0f;
            float a = u + 1.0f, b2 = u + 0.5f, cc = u - 0.5f, d = u - 1.0f;
            c[i][0] = b2 * cc * d  * (-2.0f / 3.0f);
            c[i][1] = a  * cc * d  * ( 4.0f / 3.0f);
            c[i][2] = a  * b2 * d  * (-4.0f / 3.0f);
            c[i][3] = a  * b2 * cc * ( 2.0f / 3.0f);
            sseg[i] = id;
        }
    }

    float acc[32];
    #pragma unroll
    for (int q = 0; q < 32; ++q) acc[q] = 0.0f;

    // ---- double-buffered pipeline over 4 chunks of 2 i's ----
    STAGE(0);
    __syncthreads();
    STAGE(1); COMPUTE(0); __syncthreads();
    STAGE(2); COMPUTE(1); __syncthreads();
    STAGE(3); COMPUTE(2); __syncthreads();
    COMPUTE(3);

    // ---- partials: ws[isplit][b][o] plain float4 stores (L2 write-merged) ----
    float4* wp = (float4*)(ws + (size_t)isplit * (512 * 256)
                              + (size_t)b * 256 + o_base + oh * 32);
    #pragma unroll
    for (int q = 0; q < 8; ++q)
        wp[q] = make_float4(acc[4*q], acc[4*q+1], acc[4*q+2], acc[4*q+3]);
}

__global__ __launch_bounds__(256)
void pp_reduce(const float* __restrict__ ws, float* __restrict__ out) {
    const size_t off = (size_t)blockIdx.x * 256 + threadIdx.x;  // b*256 + o
    float s = 0.0f;
    #pragma unroll
    for (int k = 0; k < NSPLIT; ++k)
        s += ws[(size_t)k * (512 * 256) + off];
    out[off] = s;
}

extern "C" void kernel_launch(void* const* d_in, const int* in_sizes, int n_in,
                              void* d_out, int out_size, void* d_ws, size_t ws_size,
                              hipStream_t stream) {
    const float* x = (const float*)d_in[0];
    const float* w = (const float*)d_in[1];
    float* out = (float*)d_out;
    float* ws  = (float*)d_ws;
    (void)ws_size; (void)n_in; (void)in_sizes; (void)out_size;

    dim3 grid(NSPLIT, 4, 4);   // (i-splits, o-tiles of 64, b-tiles of 128) = 512 blocks
    pp_partial<<<grid, 256, 0, stream>>>(x, w, ws);
    pp_reduce<<<dim3(512), 256, 0, stream>>>(ws, out);
}